// Round 12
// baseline (180.516 us; speedup 1.0000x reference)
//
#include <hip/hip_runtime.h>
#include <math.h>
#include <stdint.h>

#define T_TOK 8192
#define DIM   7168
#define NE    256
#define NGRP  8
#define TOPKN 8
#define ROUTE_SCALE 2.5f

typedef __bf16 bf16x8 __attribute__((ext_vector_type(8)));
typedef float f32x16 __attribute__((ext_vector_type(16)));

static __device__ __forceinline__ void glds16(const void* g, void* l) {
  __builtin_amdgcn_global_load_lds(
      (const __attribute__((address_space(1))) uint32_t*)g,
      (__attribute__((address_space(3))) uint32_t*)l, 16, 0, 0);
}
static __device__ __forceinline__ bf16x8 ldfrag(const void* p) {
  return __builtin_bit_cast(bf16x8, *reinterpret_cast<const uint4*>(p));
}
// 256B super-row swizzle: rows paired; 16 slots of 16B; j = granule 0..7
// (0..3 hi, 4..7 lo). Each 32-consecutive-row column read -> 2 lanes/slot
// (different super-rows) = 2-way conflict = free (m136).
static __device__ __forceinline__ int slotOf(int row, int j) {
  return ((j << 1) | (row & 1)) ^ ((row >> 1) & 15);
}
static __device__ __forceinline__ int tileOff(int row, int j) {
  return ((row >> 1) << 8) + (slotOf(row, j) << 4);   // byte offset
}

// ---- w [E][D] f32 -> wh/wl bf16 (hi + residual-lo), natural layout ---------
__global__ __launch_bounds__(256) void w_convert(const float* __restrict__ w,
                                                 uint16_t* __restrict__ wh,
                                                 uint16_t* __restrict__ wl) {
  const int e = blockIdx.x;
#pragma unroll
  for (int p = 0; p < 4; ++p) {
    const int gp = threadIdx.x + p * 256;  // granule = 8 elems
    if (gp >= DIM / 8) continue;
    const float4 a = *reinterpret_cast<const float4*>(&w[(size_t)e * DIM + gp * 8]);
    const float4 b = *reinterpret_cast<const float4*>(&w[(size_t)e * DIM + gp * 8 + 4]);
    const float src[8] = {a.x, a.y, a.z, a.w, b.x, b.y, b.z, b.w};
    __bf16 hs[8], ls[8];
#pragma unroll
    for (int u = 0; u < 8; ++u) {
      const __bf16 h = (__bf16)src[u];
      hs[u] = h;
      ls[u] = (__bf16)(src[u] - (float)h);
    }
    *reinterpret_cast<uint4*>(&wh[(size_t)e * DIM + gp * 8]) = *reinterpret_cast<const uint4*>(hs);
    *reinterpret_cast<uint4*>(&wl[(size_t)e * DIM + gp * 8]) = *reinterpret_cast<const uint4*>(ls);
  }
}

// ---- split-bf16 3-product MFMA GEMM, 2-phase m201-style schedule.
// Block 256x256, BK=32, 512 thr / 8 waves (2M x 4N), wave tile 128x64.
// Per K-step: 2 phases (kk): {12 ds_read_b128 (8 A-frag + 4 B-frag, batched
// mi=4) -> s_barrier (reads drain during wait) -> lgkmcnt(0) -> 24 MFMA}.
// Super-row swizzled LDS (2-way conflicts only). B via global_load_lds with
// inverse-swizzled source; A reg-staged f32->hi/lo. ----
template <int NSPLIT>
__global__ __launch_bounds__(512, 1) void gemm_2p(
    const float* __restrict__ x, const uint16_t* __restrict__ wh,
    const uint16_t* __restrict__ wl, float* __restrict__ partial) {
  constexpr int KH = DIM / NSPLIT;
  constexpr int NIT = KH / 32;
  __shared__ __align__(16) uint8_t As[2][32768];  // 256 rows x 128B (hi|lo)
  __shared__ __align__(16) uint8_t Bs[2][32768];

  const int tid = threadIdx.x;
  const int lane = tid & 63;
  const int l31 = lane & 31;
  const int khalf = lane >> 5;
  const int wid = tid >> 6;          // 0..7
  const int wm = wid >> 2;           // 0..1  (M half)
  const int wn = wid & 3;            // 0..3  (N quarter)

  const int b = blockIdx.x;
  const int ks = b % NSPLIT;         // NSPLIT=8: b&7 = XCD -> w K-slice/XCD ~0.9MB
  const int mblk = b / NSPLIT;
  const int m0 = mblk * 256, k0 = ks * KH;

  // A staging: thread -> row ar (0..255), 16-f32 half ah2
  const int ar = tid >> 1;
  const int ah2 = tid & 1;

  f32x16 acc[4][2];
#pragma unroll
  for (int mi = 0; mi < 4; ++mi)
#pragma unroll
    for (int nf = 0; nf < 2; ++nf)
#pragma unroll
      for (int q = 0; q < 16; ++q) acc[mi][nf][q] = 0.f;

  float4 av[4];
  auto loadA = [&](int kb) {
#pragma unroll
    for (int q = 0; q < 4; ++q)
      av[q] = *reinterpret_cast<const float4*>(
          &x[(size_t)(m0 + ar) * DIM + kb + ah2 * 16 + q * 4]);
  };
  auto writeA = [&](int buf) {
#pragma unroll
    for (int g2 = 0; g2 < 2; ++g2) {   // two 8-f32 granules
      __bf16 h8[8], l8[8];
#pragma unroll
      for (int u = 0; u < 8; ++u) {
        const float fv = reinterpret_cast<const float*>(av)[g2 * 8 + u];
        const __bf16 h = (__bf16)fv;
        h8[u] = h;
        l8[u] = (__bf16)(fv - (float)h);
      }
      const int j = ah2 * 2 + g2;      // hi granule 0..3
      *reinterpret_cast<uint4*>(&As[buf][tileOff(ar, j)]) =
          *reinterpret_cast<const uint4*>(h8);
      *reinterpret_cast<uint4*>(&As[buf][tileOff(ar, j + 4)]) =
          *reinterpret_cast<const uint4*>(l8);
    }
  };
  // B DMA: LDS linear granule g -> (super-row, slot); invert swizzle to find
  // logical (row, j); j<4 from wh, else wl. Lane-contiguous LDS dest.
  auto stageB = [&](int buf, int kb) {
#pragma unroll
    for (int h = 0; h < 4; ++h) {
      const int g = tid + h * 512;     // 0..2047
      const int sr = g >> 4;
      const int u = (g & 15) ^ (sr & 15);
      const int row = sr * 2 + (u & 1);
      const int j = u >> 1;
      const uint16_t* src = (j < 4)
          ? wh + (size_t)row * DIM + kb + j * 8
          : wl + (size_t)row * DIM + kb + (j - 4) * 8;
      glds16(src, &Bs[buf][0] + (size_t)g * 16);
    }
  };
  // one phase: all frags for kk (mi=0..3, nf=0..1) -> 24 MFMA
  auto phase = [&](int buf, int kk) {
    const int jh = kk * 2 + khalf;     // hi granule 0..3
    bf16x8 fB[2][2], fA[4][2];
#pragma unroll
    for (int nf = 0; nf < 2; ++nf) {
      const int brow = wn * 64 + nf * 32 + l31;
      fB[nf][0] = ldfrag(&Bs[buf][tileOff(brow, jh)]);
      fB[nf][1] = ldfrag(&Bs[buf][tileOff(brow, jh + 4)]);
    }
#pragma unroll
    for (int mi = 0; mi < 4; ++mi) {
      const int arow = wm * 128 + mi * 32 + l31;
      fA[mi][0] = ldfrag(&As[buf][tileOff(arow, jh)]);
      fA[mi][1] = ldfrag(&As[buf][tileOff(arow, jh + 4)]);
    }
    __builtin_amdgcn_sched_barrier(0);
    __builtin_amdgcn_s_barrier();                       // reads drain in-wait
    asm volatile("s_waitcnt lgkmcnt(0)" ::: "memory");
    __builtin_amdgcn_sched_barrier(0);
    __builtin_amdgcn_s_setprio(1);
#pragma unroll
    for (int mi = 0; mi < 4; ++mi)
#pragma unroll
      for (int nf = 0; nf < 2; ++nf) {
        acc[mi][nf] = __builtin_amdgcn_mfma_f32_32x32x16_bf16(fA[mi][0], fB[nf][0], acc[mi][nf], 0, 0, 0);
        acc[mi][nf] = __builtin_amdgcn_mfma_f32_32x32x16_bf16(fA[mi][1], fB[nf][0], acc[mi][nf], 0, 0, 0);
        acc[mi][nf] = __builtin_amdgcn_mfma_f32_32x32x16_bf16(fA[mi][0], fB[nf][1], acc[mi][nf], 0, 0, 0);
      }
    __builtin_amdgcn_s_setprio(0);
  };

  // ---- prologue: fill buffer 0 ----
  loadA(k0);
  stageB(0, k0);
  writeA(0);                                      // compiler waits av
  asm volatile("s_waitcnt vmcnt(0) lgkmcnt(0)" ::: "memory");
  __builtin_amdgcn_sched_barrier(0);
  __builtin_amdgcn_s_barrier();

  for (int it = 0; it < NIT; ++it) {
    const int cur = it & 1;
    const int nxt = cur ^ 1;
    const bool more = (it + 1) < NIT;
    // issue-early staging for next tile (in flight across both phases)
    if (more) {
      loadA(k0 + (it + 1) * 32);
      stageB(nxt, k0 + (it + 1) * 32);
    }
    phase(cur, 0);
    __builtin_amdgcn_s_barrier();
    phase(cur, 1);
    if (more) {
      writeA(nxt);                                // compiler waits av (loadA)
      asm volatile("s_waitcnt vmcnt(0) lgkmcnt(0)" ::: "memory");
      __builtin_amdgcn_sched_barrier(0);
      __builtin_amdgcn_s_barrier();
    }
  }

  float* pout = partial + (size_t)ks * T_TOK * NE;
#pragma unroll
  for (int mi = 0; mi < 4; ++mi)
#pragma unroll
    for (int nf = 0; nf < 2; ++nf) {
      const int e = wn * 64 + nf * 32 + l31;
#pragma unroll
      for (int q = 0; q < 16; ++q) {
        const int row = wm * 128 + mi * 32 + (q & 3) + 8 * (q >> 2) + 4 * khalf;
        pout[(size_t)(m0 + row) * NE + e] = acc[mi][nf][q];
      }
    }
}

// ---- split-K reduce + sigmoid + bias (pure elementwise, massively parallel)
__global__ __launch_bounds__(256) void reduce_sb(
    const float* __restrict__ partial, const float* __restrict__ bias,
    float* __restrict__ scores, int nsplit) {
  const size_t i4 = (size_t)blockIdx.x * 256 + threadIdx.x;  // float4 chunk id
  float4 v = reinterpret_cast<const float4*>(partial)[i4];
#pragma unroll 8
  for (int s2 = 1; s2 < nsplit; ++s2) {
    const float4 u = reinterpret_cast<const float4*>(
        partial + (size_t)s2 * T_TOK * NE)[i4];
    v.x += u.x; v.y += u.y; v.z += u.z; v.w += u.w;
  }
  const int e = (int)((i4 * 4) & (NE - 1));
  const float4 bv = *reinterpret_cast<const float4*>(&bias[e]);
  float4 o;
  o.x = 1.f / (1.f + expf(-v.x)) + bv.x;
  o.y = 1.f / (1.f + expf(-v.y)) + bv.y;
  o.z = 1.f / (1.f + expf(-v.z)) + bv.z;
  o.w = 1.f / (1.f + expf(-v.w)) + bv.w;
  reinterpret_cast<float4*>(scores)[i4] = o;
}

// ---- group scores + top-4 groups + top-8 experts, exact serial reference
// semantics (strict >, lowest index ties; 0.0-candidates from lowest
// unselected group ascending). 1 thread/token. ----
__global__ __launch_bounds__(64) void select_topk3(
    const float* __restrict__ scores, float* __restrict__ out) {
  const int t = blockIdx.x * 64 + threadIdx.x;
  const float* s = scores + (size_t)t * NE;
  const float NEG_INF = -__builtin_inff();

  float g8[8];
#pragma unroll
  for (int g = 0; g < 8; ++g) {
    float v1 = NEG_INF, v2 = NEG_INF;
#pragma unroll
    for (int c = 0; c < 8; ++c) {
      const float4 u = *reinterpret_cast<const float4*>(&s[g * 32 + c * 4]);
      const float sv[4] = {u.x, u.y, u.z, u.w};
#pragma unroll
      for (int k = 0; k < 4; ++k) {
        v2 = fmaxf(v2, fminf(v1, sv[k]));
        v1 = fmaxf(v1, sv[k]);
      }
    }
    g8[g] = v1 + v2;
  }

  unsigned selmask = 0;
  for (int r = 0; r < 4; ++r) {
    float best = NEG_INF;
    int bg = 0;
#pragma unroll
    for (int g = 0; g < 8; ++g)
      if (!((selmask >> g) & 1u) && g8[g] > best) { best = g8[g]; bg = g; }
    selmask |= (1u << bg);
  }

  unsigned mrem = selmask;
  const int sel0 = __ffs(mrem) - 1; mrem &= mrem - 1;
  const int sel1 = __ffs(mrem) - 1; mrem &= mrem - 1;
  const int sel2 = __ffs(mrem) - 1; mrem &= mrem - 1;
  const int sel3 = __ffs(mrem) - 1;
  const int gz = __ffs(~selmask & 0xffu) - 1;

  float ca[4][32];
#pragma unroll
  for (int c = 0; c < 8; ++c) {
    const float4 u0 = *reinterpret_cast<const float4*>(&s[sel0 * 32 + c * 4]);
    const float4 u1 = *reinterpret_cast<const float4*>(&s[sel1 * 32 + c * 4]);
    const float4 u2 = *reinterpret_cast<const float4*>(&s[sel2 * 32 + c * 4]);
    const float4 u3 = *reinterpret_cast<const float4*>(&s[sel3 * 32 + c * 4]);
    ca[0][c * 4 + 0] = u0.x; ca[0][c * 4 + 1] = u0.y; ca[0][c * 4 + 2] = u0.z; ca[0][c * 4 + 3] = u0.w;
    ca[1][c * 4 + 0] = u1.x; ca[1][c * 4 + 1] = u1.y; ca[1][c * 4 + 2] = u1.z; ca[1][c * 4 + 3] = u1.w;
    ca[2][c * 4 + 0] = u2.x; ca[2][c * 4 + 1] = u2.y; ca[2][c * 4 + 2] = u2.z; ca[2][c * 4 + 3] = u2.w;
    ca[3][c * 4 + 0] = u3.x; ca[3][c * 4 + 1] = u3.y; ca[3][c * 4 + 2] = u3.z; ca[3][c * 4 + 3] = u3.w;
  }

  uint32_t ex[4] = {0, 0, 0, 0};
  int zcnt = 0;
  for (int r = 0; r < TOPKN; ++r) {
    float best = NEG_INF;
    int bq = 0, bi = 0;
#pragma unroll
    for (int q = 0; q < 4; ++q)
#pragma unroll
      for (int i = 0; i < 32; ++i) {
        const float v = ca[q][i];
        if (!((ex[q] >> i) & 1u) && v > best) { best = v; bq = q; bi = i; }
      }
    const int bg = (bq == 0) ? sel0 : (bq == 1) ? sel1 : (bq == 2) ? sel2 : sel3;
    const int be = bg * 32 + bi;
    const int ze = gz * 32 + zcnt;
    const bool takeReal = (best > 0.0f) || (best == 0.0f && be < ze);
    if (takeReal) {
#pragma unroll
      for (int q = 0; q < 4; ++q)
        if (q == bq) ex[q] |= 1u << bi;
      out[(size_t)t * TOPKN + r] = best * ROUTE_SCALE;
      out[(size_t)T_TOK * TOPKN + (size_t)t * TOPKN + r] = (float)be;
    } else {
      out[(size_t)t * TOPKN + r] = s[ze] * ROUTE_SCALE;
      out[(size_t)T_TOK * TOPKN + (size_t)t * TOPKN + r] = (float)ze;
      ++zcnt;
    }
  }
}

extern "C" void kernel_launch(void* const* d_in, const int* in_sizes, int n_in,
                              void* d_out, int out_size, void* d_ws, size_t ws_size,
                              hipStream_t stream) {
  const float* x = (const float*)d_in[0];
  const float* w = (const float*)d_in[1];
  const float* bias = (const float*)d_in[2];
  float* out = (float*)d_out;

  const size_t SC = (size_t)T_TOK * NE;
  const size_t WBYTES = (size_t)NE * DIM * 2;
  const size_t need8 = 8 * SC * 4 + 2 * WBYTES;
  const size_t need4 = 4 * SC * 4 + 2 * WBYTES;
  const int nsplit = (ws_size >= need8) ? 8 : (ws_size >= need4) ? 4 : 2;

  float* part = (float*)d_ws;
  uint16_t* whp = (uint16_t*)(part + (size_t)nsplit * SC);
  uint16_t* wlp = whp + (size_t)NE * DIM;
  float* scores = part;  // reduce overlays partial[0] (same-thread RAW only)

  w_convert<<<NE, 256, 0, stream>>>(w, whp, wlp);
  if (nsplit == 8)
    gemm_2p<8><<<256, 512, 0, stream>>>(x, whp, wlp, part);
  else if (nsplit == 4)
    gemm_2p<4><<<128, 512, 0, stream>>>(x, whp, wlp, part);
  else
    gemm_2p<2><<<64, 512, 0, stream>>>(x, whp, wlp, part);
  reduce_sb<<<(int)(SC / 4 / 256), 256, 0, stream>>>(part, bias, scores, nsplit);
  select_topk3<<<T_TOK / 64, 64, 0, stream>>>(scores, out);
}

// Round 13
// 154.287 us; speedup vs baseline: 1.1700x; 1.1700x over previous
//
#include <hip/hip_runtime.h>
#include <math.h>
#include <stdint.h>

#define T_TOK 8192
#define DIM   7168
#define NE    256
#define NGRP  8
#define TOPKN 8
#define ROUTE_SCALE 2.5f

typedef __bf16 bf16x8 __attribute__((ext_vector_type(8)));
typedef float f32x16 __attribute__((ext_vector_type(16)));

static __device__ __forceinline__ void glds16(const void* g, void* l) {
  __builtin_amdgcn_global_load_lds(
      (const __attribute__((address_space(1))) uint32_t*)g,
      (__attribute__((address_space(3))) uint32_t*)l, 16, 0, 0);
}
static __device__ __forceinline__ bf16x8 ldfrag(const void* p) {
  return __builtin_bit_cast(bf16x8, *reinterpret_cast<const uint4*>(p));
}
// LDS layout: row*128B, granule j (0..3 hi, 4..7 lo) at slot j^(row&7).
static __device__ __forceinline__ int tileOff(int row, int j) {
  return (row << 7) + ((j ^ (row & 7)) << 4);
}

// ---- w [E][D] f32 -> wh/wl bf16 (hi + residual-lo), natural layout ---------
__global__ __launch_bounds__(256) void w_convert(const float* __restrict__ w,
                                                 uint16_t* __restrict__ wh,
                                                 uint16_t* __restrict__ wl) {
  const int e = blockIdx.x;
#pragma unroll
  for (int p = 0; p < 4; ++p) {
    const int gp = threadIdx.x + p * 256;  // granule = 8 elems
    if (gp >= DIM / 8) continue;
    const float4 a = *reinterpret_cast<const float4*>(&w[(size_t)e * DIM + gp * 8]);
    const float4 b = *reinterpret_cast<const float4*>(&w[(size_t)e * DIM + gp * 8 + 4]);
    const float src[8] = {a.x, a.y, a.z, a.w, b.x, b.y, b.z, b.w};
    __bf16 hs[8], ls[8];
#pragma unroll
    for (int u = 0; u < 8; ++u) {
      const __bf16 h = (__bf16)src[u];
      hs[u] = h;
      ls[u] = (__bf16)(src[u] - (float)h);
    }
    *reinterpret_cast<uint4*>(&wh[(size_t)e * DIM + gp * 8]) = *reinterpret_cast<const uint4*>(hs);
    *reinterpret_cast<uint4*>(&wl[(size_t)e * DIM + gp * 8]) = *reinterpret_cast<const uint4*>(ls);
  }
}

// ---- split-bf16 3-product MFMA GEMM, barrier-minimal free-run schedule.
// Block 256x256, BK=32, 512 thr / 8 waves (2M x 4N), wave tile 128x64,
// double-buffered 128 KB LDS. ONE __syncthreads per K-step (the drain);
// no phase barriers -> waves drift into different phases, so the CU-shared
// LDS pipe overlaps the per-SIMD matrix pipes (m114). Compiler schedules
// ds_read->MFMA with fine-grained lgkmcnt (m97). Reads hit buf cur; A-writes
// and B-DMA hit buf nxt -> no intra-iter cross-wave hazard. ----
template <int NSPLIT>
__global__ __launch_bounds__(512, 1) void gemm_fr(
    const float* __restrict__ x, const uint16_t* __restrict__ wh,
    const uint16_t* __restrict__ wl, float* __restrict__ partial) {
  constexpr int KH = DIM / NSPLIT;
  constexpr int NIT = KH / 32;
  __shared__ __align__(16) uint8_t As[2][32768];  // 256 rows x 128B (hi|lo)
  __shared__ __align__(16) uint8_t Bs[2][32768];

  const int tid = threadIdx.x;
  const int lane = tid & 63;
  const int l31 = lane & 31;
  const int khalf = lane >> 5;
  const int wid = tid >> 6;          // 0..7
  const int wm = wid >> 2;           // 0..1  (M half)
  const int wn = wid & 3;            // 0..3  (N quarter)

  const int b = blockIdx.x;
  const int ks = b % NSPLIT;         // NSPLIT=8: b&7 = XCD -> w K-slice/XCD ~0.9MB
  const int mblk = b / NSPLIT;
  const int m0 = mblk * 256, k0 = ks * KH;

  // A staging: 8 lanes/row (coalesced 128B rows); row r0+32q, f32 16B-chunk c
  const int r0 = tid >> 3;           // 0..63
  const int ac = tid & 7;            // f32 granule (16B)
  const int aj = ac >> 1;            // bf16 granule 0..3
  const int ah = ac & 1;             // 8B half within granule

  f32x16 acc[4][2];
#pragma unroll
  for (int mi = 0; mi < 4; ++mi)
#pragma unroll
    for (int nf = 0; nf < 2; ++nf)
#pragma unroll
      for (int q = 0; q < 16; ++q) acc[mi][nf][q] = 0.f;

  float4 av[4];
  auto loadA = [&](int kb) {
#pragma unroll
    for (int q = 0; q < 4; ++q)
      av[q] = *reinterpret_cast<const float4*>(
          &x[(size_t)(m0 + r0 + q * 64) * DIM + kb + ac * 4]);
  };
  auto writeA = [&](int buf) {
#pragma unroll
    for (int q = 0; q < 4; ++q) {
      const int row = r0 + q * 64;
      const float s[4] = {av[q].x, av[q].y, av[q].z, av[q].w};
      __bf16 hi[4], lo[4];
#pragma unroll
      for (int u = 0; u < 4; ++u) {
        hi[u] = (__bf16)s[u];
        lo[u] = (__bf16)(s[u] - (float)hi[u]);
      }
      *reinterpret_cast<uint2*>(&As[buf][tileOff(row, aj) + ah * 8]) =
          *reinterpret_cast<const uint2*>(hi);
      *reinterpret_cast<uint2*>(&As[buf][tileOff(row, aj + 4) + ah * 8]) =
          *reinterpret_cast<const uint2*>(lo);
    }
  };
  // B DMA: LDS granule g (row=g>>3, slot=g&7) <- logical j=(g&7)^(row&7);
  // j<4 from wh, else wl. Lane-contiguous LDS dest (linear), swizzle on src.
  auto stageB = [&](int buf, int kb) {
#pragma unroll
    for (int h = 0; h < 4; ++h) {
      const int g = tid + h * 512;     // 0..2047
      const int row = g >> 3;
      const int j = (g & 7) ^ (row & 7);
      const uint16_t* src = (j < 4)
          ? wh + (size_t)row * DIM + kb + j * 8
          : wl + (size_t)row * DIM + kb + (j - 4) * 8;
      glds16(src, &Bs[buf][0] + (size_t)g * 16);
    }
  };
  // one phase: all frags for kk (mi=0..3, nf=0..1) -> 24 MFMA; no barriers,
  // compiler inserts fine-grained lgkmcnt between reads and MFMAs.
  auto phase = [&](int buf, int kk) {
    const int jh = kk * 2 + khalf;     // hi granule 0..3
    bf16x8 fB[2][2], fA[4][2];
#pragma unroll
    for (int nf = 0; nf < 2; ++nf) {
      const int brow = wn * 64 + nf * 32 + l31;
      fB[nf][0] = ldfrag(&Bs[buf][tileOff(brow, jh)]);
      fB[nf][1] = ldfrag(&Bs[buf][tileOff(brow, jh + 4)]);
    }
#pragma unroll
    for (int mi = 0; mi < 4; ++mi) {
      const int arow = wm * 128 + mi * 32 + l31;
      fA[mi][0] = ldfrag(&As[buf][tileOff(arow, jh)]);
      fA[mi][1] = ldfrag(&As[buf][tileOff(arow, jh + 4)]);
    }
    __builtin_amdgcn_s_setprio(1);
#pragma unroll
    for (int mi = 0; mi < 4; ++mi)
#pragma unroll
      for (int nf = 0; nf < 2; ++nf) {
        acc[mi][nf] = __builtin_amdgcn_mfma_f32_32x32x16_bf16(fA[mi][0], fB[nf][0], acc[mi][nf], 0, 0, 0);
        acc[mi][nf] = __builtin_amdgcn_mfma_f32_32x32x16_bf16(fA[mi][1], fB[nf][0], acc[mi][nf], 0, 0, 0);
        acc[mi][nf] = __builtin_amdgcn_mfma_f32_32x32x16_bf16(fA[mi][0], fB[nf][1], acc[mi][nf], 0, 0, 0);
      }
    __builtin_amdgcn_s_setprio(0);
  };

  // ---- prologue: fill buffer 0 ----
  loadA(k0);
  stageB(0, k0);
  writeA(0);                 // compiler waits on av loads only
  __syncthreads();           // drains DMA + ds_writes; buffer 0 ready

  for (int it = 0; it < NIT; ++it) {
    const int cur = it & 1;
    const int nxt = cur ^ 1;
    const bool more = (it + 1) < NIT;
    if (more) {
      loadA(k0 + (it + 1) * 32);      // A f32 regs, in flight over compute
      stageB(nxt, k0 + (it + 1) * 32);// B DMA -> other buffer, in flight
    }
    phase(cur, 0);
    phase(cur, 1);
    if (more) {
      writeA(nxt);                    // waits av (vmcnt(8): DMAs keep flying)
      __syncthreads();                // the ONE drain: vmcnt0+lgkm0+barrier
    }
  }

  float* pout = partial + (size_t)ks * T_TOK * NE;
#pragma unroll
  for (int mi = 0; mi < 4; ++mi)
#pragma unroll
    for (int nf = 0; nf < 2; ++nf) {
      const int e = wn * 64 + nf * 32 + l31;
#pragma unroll
      for (int q = 0; q < 16; ++q) {
        const int row = wm * 128 + mi * 32 + (q & 3) + 8 * (q >> 2) + 4 * khalf;
        pout[(size_t)(m0 + row) * NE + e] = acc[mi][nf][q];
      }
    }
}

// ---- split-K reduce + sigmoid + bias (pure elementwise, massively parallel)
__global__ __launch_bounds__(256) void reduce_sb(
    const float* __restrict__ partial, const float* __restrict__ bias,
    float* __restrict__ scores, int nsplit) {
  const size_t i4 = (size_t)blockIdx.x * 256 + threadIdx.x;  // float4 chunk id
  float4 v = reinterpret_cast<const float4*>(partial)[i4];
#pragma unroll 8
  for (int s2 = 1; s2 < nsplit; ++s2) {
    const float4 u = reinterpret_cast<const float4*>(
        partial + (size_t)s2 * T_TOK * NE)[i4];
    v.x += u.x; v.y += u.y; v.z += u.z; v.w += u.w;
  }
  const int e = (int)((i4 * 4) & (NE - 1));
  const float4 bv = *reinterpret_cast<const float4*>(&bias[e]);
  float4 o;
  o.x = 1.f / (1.f + expf(-v.x)) + bv.x;
  o.y = 1.f / (1.f + expf(-v.y)) + bv.y;
  o.z = 1.f / (1.f + expf(-v.z)) + bv.z;
  o.w = 1.f / (1.f + expf(-v.w)) + bv.w;
  reinterpret_cast<float4*>(scores)[i4] = o;
}

// ---- group scores + top-4 groups + top-8 experts, exact serial reference
// semantics (strict >, lowest index ties; 0.0-candidates from lowest
// unselected group ascending). 1 thread/token. ----
__global__ __launch_bounds__(64) void select_topk3(
    const float* __restrict__ scores, float* __restrict__ out) {
  const int t = blockIdx.x * 64 + threadIdx.x;
  const float* s = scores + (size_t)t * NE;
  const float NEG_INF = -__builtin_inff();

  float g8[8];
#pragma unroll
  for (int g = 0; g < 8; ++g) {
    float v1 = NEG_INF, v2 = NEG_INF;
#pragma unroll
    for (int c = 0; c < 8; ++c) {
      const float4 u = *reinterpret_cast<const float4*>(&s[g * 32 + c * 4]);
      const float sv[4] = {u.x, u.y, u.z, u.w};
#pragma unroll
      for (int k = 0; k < 4; ++k) {
        v2 = fmaxf(v2, fminf(v1, sv[k]));
        v1 = fmaxf(v1, sv[k]);
      }
    }
    g8[g] = v1 + v2;
  }

  unsigned selmask = 0;
  for (int r = 0; r < 4; ++r) {
    float best = NEG_INF;
    int bg = 0;
#pragma unroll
    for (int g = 0; g < 8; ++g)
      if (!((selmask >> g) & 1u) && g8[g] > best) { best = g8[g]; bg = g; }
    selmask |= (1u << bg);
  }

  unsigned mrem = selmask;
  const int sel0 = __ffs(mrem) - 1; mrem &= mrem - 1;
  const int sel1 = __ffs(mrem) - 1; mrem &= mrem - 1;
  const int sel2 = __ffs(mrem) - 1; mrem &= mrem - 1;
  const int sel3 = __ffs(mrem) - 1;
  const int gz = __ffs(~selmask & 0xffu) - 1;

  float ca[4][32];
#pragma unroll
  for (int c = 0; c < 8; ++c) {
    const float4 u0 = *reinterpret_cast<const float4*>(&s[sel0 * 32 + c * 4]);
    const float4 u1 = *reinterpret_cast<const float4*>(&s[sel1 * 32 + c * 4]);
    const float4 u2 = *reinterpret_cast<const float4*>(&s[sel2 * 32 + c * 4]);
    const float4 u3 = *reinterpret_cast<const float4*>(&s[sel3 * 32 + c * 4]);
    ca[0][c * 4 + 0] = u0.x; ca[0][c * 4 + 1] = u0.y; ca[0][c * 4 + 2] = u0.z; ca[0][c * 4 + 3] = u0.w;
    ca[1][c * 4 + 0] = u1.x; ca[1][c * 4 + 1] = u1.y; ca[1][c * 4 + 2] = u1.z; ca[1][c * 4 + 3] = u1.w;
    ca[2][c * 4 + 0] = u2.x; ca[2][c * 4 + 1] = u2.y; ca[2][c * 4 + 2] = u2.z; ca[2][c * 4 + 3] = u2.w;
    ca[3][c * 4 + 0] = u3.x; ca[3][c * 4 + 1] = u3.y; ca[3][c * 4 + 2] = u3.z; ca[3][c * 4 + 3] = u3.w;
  }

  uint32_t ex[4] = {0, 0, 0, 0};
  int zcnt = 0;
  for (int r = 0; r < TOPKN; ++r) {
    float best = NEG_INF;
    int bq = 0, bi = 0;
#pragma unroll
    for (int q = 0; q < 4; ++q)
#pragma unroll
      for (int i = 0; i < 32; ++i) {
        const float v = ca[q][i];
        if (!((ex[q] >> i) & 1u) && v > best) { best = v; bq = q; bi = i; }
      }
    const int bg = (bq == 0) ? sel0 : (bq == 1) ? sel1 : (bq == 2) ? sel2 : sel3;
    const int be = bg * 32 + bi;
    const int ze = gz * 32 + zcnt;
    const bool takeReal = (best > 0.0f) || (best == 0.0f && be < ze);
    if (takeReal) {
#pragma unroll
      for (int q = 0; q < 4; ++q)
        if (q == bq) ex[q] |= 1u << bi;
      out[(size_t)t * TOPKN + r] = best * ROUTE_SCALE;
      out[(size_t)T_TOK * TOPKN + (size_t)t * TOPKN + r] = (float)be;
    } else {
      out[(size_t)t * TOPKN + r] = s[ze] * ROUTE_SCALE;
      out[(size_t)T_TOK * TOPKN + (size_t)t * TOPKN + r] = (float)ze;
      ++zcnt;
    }
  }
}

extern "C" void kernel_launch(void* const* d_in, const int* in_sizes, int n_in,
                              void* d_out, int out_size, void* d_ws, size_t ws_size,
                              hipStream_t stream) {
  const float* x = (const float*)d_in[0];
  const float* w = (const float*)d_in[1];
  const float* bias = (const float*)d_in[2];
  float* out = (float*)d_out;

  const size_t SC = (size_t)T_TOK * NE;
  const size_t WBYTES = (size_t)NE * DIM * 2;
  const size_t need8 = 8 * SC * 4 + 2 * WBYTES;
  const size_t need4 = 4 * SC * 4 + 2 * WBYTES;
  const int nsplit = (ws_size >= need8) ? 8 : (ws_size >= need4) ? 4 : 2;

  float* part = (float*)d_ws;
  uint16_t* whp = (uint16_t*)(part + (size_t)nsplit * SC);
  uint16_t* wlp = whp + (size_t)NE * DIM;
  float* scores = part;  // reduce overlays partial[0] (same-thread RAW only)

  w_convert<<<NE, 256, 0, stream>>>(w, whp, wlp);
  if (nsplit == 8)
    gemm_fr<8><<<256, 512, 0, stream>>>(x, whp, wlp, part);
  else if (nsplit == 4)
    gemm_fr<4><<<128, 512, 0, stream>>>(x, whp, wlp, part);
  else
    gemm_fr<2><<<64, 512, 0, stream>>>(x, whp, wlp, part);
  reduce_sb<<<(int)(SC / 4 / 256), 256, 0, stream>>>(part, bias, scores, nsplit);
  select_topk3<<<T_TOK / 64, 64, 0, stream>>>(scores, out);
}